// Round 11
// baseline (83.796 us; speedup 1.0000x reference)
//
#include <hip/hip_runtime.h>

// Radon3D loss on MI355X — project the DIFFERENCE volume (radon is linear).
// Geometry (D=H=W=64, 120 angles over [0,120] deg): L=91, pad top=left=13.
//   ix(i,j) = 45*c*linj + 32 + 45*s - s*i,  iy(i,j) = 45*s*linj + 32 - 45*c + c*i
//   (unit steps in i: the 0.5*(L-1) unnormalization cancels the linspace step)
// R4-R10 evidence: every LDS-staging variant (occupancy x2, bytes /2, ILP x2,
// swizzle) pins the main kernel at ~28-34 us vs an ~11 us LDS floor. This
// round REMOVES the LDS structure: fp8 wide canvases are built ONCE in global
// (d_ws, 591 KB, L2-resident; kernel boundary = device-scope release), and
// the projection streams corners via 2 x global_load_dwordx4 per iter.
// Wide cell (y,x) = 16 B = [P8(y-1,x-1) | P8(y-1,x)], P8 = 8-slice fp8 pack,
// zero outside [0,64)^2 == map_coordinates mode='constant', cval=0.
// Coords shifted +1 (nonneg), clamped to [0,65].
#define DD 64
#define NA 120
#define LL 91
#define PS 67
#define PSTR 69
#define NCELL (PS * PSTR)     // 4623 cells
#define NCELLP 4624           // padded per-group stride
#define NSL 8                 // slices per group (fp8 byte-lanes)
#define NGRP (64 / NSL)       // 8 slice groups
#define JT 96                 // j-lanes per angle (91 active)
#define PTHR (2 * JT)         // 192 threads: (i-half, j)
#define PBLKS (NGRP * NA)     // 960 projection blocks
#define BLD_BLK ((NCELLP + 255) / 256)   // 19 build blocks per group

typedef float f32x2 __attribute__((ext_vector_type(2)));

// ---------------- canvas build: one pass, no races, no barriers ------------
__global__ __launch_bounds__(256) void build_canvas_kernel(
    const float* __restrict__ vout, const float* __restrict__ vgt,
    uint4* __restrict__ C)
{
    const int bid = blockIdx.x;
    const int g = bid / BLD_BLK;               // slice group 0..7
    const int cell = (bid - g * BLD_BLK) * 256 + threadIdx.x;
    if (cell >= NCELL) return;
    const int y = cell / PSTR;
    const int x = cell - y * PSTR;
    const int d = y - 1;                       // image row
    const int w0 = x - 1, w1 = x;              // lo / hi pixel columns
    uint4 val = make_uint4(0u, 0u, 0u, 0u);
    if ((unsigned)d < DD) {
        const int rowbase = d * 4096 + g * NSL * 64;
        if ((unsigned)w0 < DD) {
            int p0 = 0, p1 = 0;
            float df[NSL];
            #pragma unroll
            for (int k = 0; k < NSL; ++k)
                df[k] = vout[rowbase + 64 * k + w0] - vgt[rowbase + 64 * k + w0];
            p0 = __builtin_amdgcn_cvt_pk_fp8_f32(df[0], df[1], p0, false);
            p0 = __builtin_amdgcn_cvt_pk_fp8_f32(df[2], df[3], p0, true);
            p1 = __builtin_amdgcn_cvt_pk_fp8_f32(df[4], df[5], p1, false);
            p1 = __builtin_amdgcn_cvt_pk_fp8_f32(df[6], df[7], p1, true);
            val.x = (unsigned)p0; val.y = (unsigned)p1;
        }
        if ((unsigned)w1 < DD) {
            int p0 = 0, p1 = 0;
            float df[NSL];
            #pragma unroll
            for (int k = 0; k < NSL; ++k)
                df[k] = vout[rowbase + 64 * k + w1] - vgt[rowbase + 64 * k + w1];
            p0 = __builtin_amdgcn_cvt_pk_fp8_f32(df[0], df[1], p0, false);
            p0 = __builtin_amdgcn_cvt_pk_fp8_f32(df[2], df[3], p0, true);
            p1 = __builtin_amdgcn_cvt_pk_fp8_f32(df[4], df[5], p1, false);
            p1 = __builtin_amdgcn_cvt_pk_fp8_f32(df[6], df[7], p1, true);
            val.z = (unsigned)p0; val.w = (unsigned)p1;
        }
    }
    C[g * NCELLP + cell] = val;
}

// ---------------- projection: pure L2 streaming, no LDS canvas -------------
__global__ __launch_bounds__(PTHR) void radon_proj_kernel(
    const uint4* __restrict__ C, float* __restrict__ out)
{
    __shared__ float colsum[LL][NSL];    // i-half-0 partials, 2.9 KB
    __shared__ float wsum[PTHR / 64];

    const int bid = blockIdx.x;
    const int g = bid / NA;              // slice group 0..7
    const int a = bid - g * NA;          // angle 0..119
    const int t = threadIdx.x;
    const int half = t / JT;             // i-half 0/1
    const int j = t - half * JT;

    const float theta = (float)a * (float)(3.14159265358979323846 * 120.0 / 119.0 / 180.0);
    const float c = cosf(theta), sn = sinf(theta);

    float acc[NSL] = {0.f, 0.f, 0.f, 0.f, 0.f, 0.f, 0.f, 0.f};
    if (j < LL) {
        const float linj = fmaf((float)j, 2.0f / 90.0f, -1.0f);
        // +1 shift: coords in [0,65] after clamp; canvas row/col 0 is border
        const float bx1 = fmaf(c,  linj, 1.0f) * 45.0f - 12.0f + 45.0f * sn;
        const float by1 = fmaf(sn, linj, 1.0f) * 45.0f - 12.0f - 45.0f * c;
        const uint4* __restrict__ Cg = C + g * NCELLP;
        const int i0 = half ? 46 : 0;
        const int i1 = half ? LL : 46;
        #pragma unroll 3
        for (int i = i0; i < i1; ++i) {
            const float xs = fminf(fmaxf(fmaf(-(float)i, sn, bx1), 0.0f), 65.0f);
            const float ys = fminf(fmaxf(fmaf( (float)i, c,  by1), 0.0f), 65.0f);
            const int ix = (int)xs;      // trunc == floor (nonneg)
            const int iy = (int)ys;
            const float wx = xs - (float)ix;
            const float wy = ys - (float)iy;
            const float ux = 1.f - wx, uy = 1.f - wy;
            const float w00 = ux * uy, w01 = wx * uy;
            const float w10 = ux * wy, w11 = wx * wy;
            const int ci = iy * PSTR + ix;
            const uint4 q0 = Cg[ci];          // row y  : [P8(x-1) | P8(x)]
            const uint4 q1 = Cg[ci + PSTR];   // row y+1: [P8(x-1) | P8(x)]
            f32x2 v;
            v = __builtin_amdgcn_cvt_pk_f32_fp8(q0.x, false); acc[0] = fmaf(w00, v.x, acc[0]); acc[1] = fmaf(w00, v.y, acc[1]);
            v = __builtin_amdgcn_cvt_pk_f32_fp8(q0.x, true);  acc[2] = fmaf(w00, v.x, acc[2]); acc[3] = fmaf(w00, v.y, acc[3]);
            v = __builtin_amdgcn_cvt_pk_f32_fp8(q0.y, false); acc[4] = fmaf(w00, v.x, acc[4]); acc[5] = fmaf(w00, v.y, acc[5]);
            v = __builtin_amdgcn_cvt_pk_f32_fp8(q0.y, true);  acc[6] = fmaf(w00, v.x, acc[6]); acc[7] = fmaf(w00, v.y, acc[7]);
            v = __builtin_amdgcn_cvt_pk_f32_fp8(q0.z, false); acc[0] = fmaf(w01, v.x, acc[0]); acc[1] = fmaf(w01, v.y, acc[1]);
            v = __builtin_amdgcn_cvt_pk_f32_fp8(q0.z, true);  acc[2] = fmaf(w01, v.x, acc[2]); acc[3] = fmaf(w01, v.y, acc[3]);
            v = __builtin_amdgcn_cvt_pk_f32_fp8(q0.w, false); acc[4] = fmaf(w01, v.x, acc[4]); acc[5] = fmaf(w01, v.y, acc[5]);
            v = __builtin_amdgcn_cvt_pk_f32_fp8(q0.w, true);  acc[6] = fmaf(w01, v.x, acc[6]); acc[7] = fmaf(w01, v.y, acc[7]);
            v = __builtin_amdgcn_cvt_pk_f32_fp8(q1.x, false); acc[0] = fmaf(w10, v.x, acc[0]); acc[1] = fmaf(w10, v.y, acc[1]);
            v = __builtin_amdgcn_cvt_pk_f32_fp8(q1.x, true);  acc[2] = fmaf(w10, v.x, acc[2]); acc[3] = fmaf(w10, v.y, acc[3]);
            v = __builtin_amdgcn_cvt_pk_f32_fp8(q1.y, false); acc[4] = fmaf(w10, v.x, acc[4]); acc[5] = fmaf(w10, v.y, acc[5]);
            v = __builtin_amdgcn_cvt_pk_f32_fp8(q1.y, true);  acc[6] = fmaf(w10, v.x, acc[6]); acc[7] = fmaf(w10, v.y, acc[7]);
            v = __builtin_amdgcn_cvt_pk_f32_fp8(q1.z, false); acc[0] = fmaf(w11, v.x, acc[0]); acc[1] = fmaf(w11, v.y, acc[1]);
            v = __builtin_amdgcn_cvt_pk_f32_fp8(q1.z, true);  acc[2] = fmaf(w11, v.x, acc[2]); acc[3] = fmaf(w11, v.y, acc[3]);
            v = __builtin_amdgcn_cvt_pk_f32_fp8(q1.w, false); acc[4] = fmaf(w11, v.x, acc[4]); acc[5] = fmaf(w11, v.y, acc[5]);
            v = __builtin_amdgcn_cvt_pk_f32_fp8(q1.w, true);  acc[6] = fmaf(w11, v.x, acc[6]); acc[7] = fmaf(w11, v.y, acc[7]);
        }
    }

    // combine i-halves per column, THEN abs (abs needs the full i-sum)
    if (half == 0 && j < LL) {
        #pragma unroll
        for (int k = 0; k < NSL; ++k) colsum[j][k] = acc[k];
    }
    __syncthreads();
    float val = 0.f;
    if (half == 1 && j < LL) {
        #pragma unroll
        for (int k = 0; k < NSL; ++k)
            val += fabsf(colsum[j][k] + acc[k]);
    }

    // block reduction (3 waves) + one scaled atomic per block
    #pragma unroll
    for (int off = 32; off > 0; off >>= 1)
        val += __shfl_down(val, off);
    const int wave = t >> 6, lane = t & 63;
    if (lane == 0) wsum[wave] = val;
    __syncthreads();
    if (t == 0) {
        float v = 0.f;
        #pragma unroll
        for (int wv = 0; wv < PTHR / 64; ++wv) v += wsum[wv];
        atomicAdd(out, v * (1.0f / (float)(NA * LL)));
    }
}

extern "C" void kernel_launch(void* const* d_in, const int* in_sizes, int n_in,
                              void* d_out, int out_size, void* d_ws, size_t ws_size,
                              hipStream_t stream) {
    const float* vout = (const float*)d_in[0];
    const float* vgt  = (const float*)d_in[1];
    float* out = (float*)d_out;
    uint4* canvas = (uint4*)d_ws;    // 8 * 4624 * 16 B = 591 KB

    hipMemsetAsync(out, 0, sizeof(float), stream);
    build_canvas_kernel<<<NGRP * BLD_BLK, 256, 0, stream>>>(vout, vgt, canvas);
    radon_proj_kernel<<<PBLKS, PTHR, 0, stream>>>(canvas, out);
}